// Round 8
// baseline (360.217 us; speedup 1.0000x reference)
//
#include <hip/hip_runtime.h>
#include <stdint.h>

#define BN_EPS 1e-3f

// ============================================================
// Weight prep (separate tiny dispatch; stream order guarantees
// visibility to mono_k):
//  - w1s[864]: sign floats (unused by mono_k, kept verbatim/harmless)
//  - w2p/w3p/w4p: bit-packed signs, bit=1 <=> w<0, layout [(tap*CINW+wi)][COUT]
// ============================================================
template <int CIN, int COUT>
__device__ inline void packw(const float* __restrict__ w, uint32_t* __restrict__ wp, int idx) {
    const int CINW = CIN / 32;
    int co = idx % COUT;
    int t2 = idx / COUT;
    int wi = t2 % CINW;
    int tap = t2 / CINW;
    uint32_t word = 0;
#pragma unroll
    for (int bb = 0; bb < 32; bb++) {
        float val = w[((tap * CIN) + wi * 32 + bb) * COUT + co];
        word |= (uint32_t)(val < 0.f) << bb;
    }
    wp[idx] = word;
}

__global__ void pack_all(const float* __restrict__ w1, const float* __restrict__ w2,
                         const float* __restrict__ w3, const float* __restrict__ w4,
                         float* __restrict__ w1s, uint32_t* __restrict__ w2p,
                         uint32_t* __restrict__ w3p, uint32_t* __restrict__ w4p) {
    int idx = blockIdx.x * 256 + threadIdx.x;
    if (idx < 864) {
        w1s[idx] = (w1[idx] < 0.f) ? -1.f : 1.f;
        return;
    }
    idx -= 864;
    if (idx < 576) { packw<32, 64>(w2, w2p, idx); return; }
    idx -= 576;
    if (idx < 2304) { packw<64, 128>(w3, w3p, idx); return; }
    idx -= 2304;
    if (idx < 9216) { packw<128, 256>(w4, w4p, idx); return; }
}

// ============================================================
// MONO kernel: conv1+pool+bn+sign -> bconv2 -> bconv3 -> bconv4, one
// dispatch, NO grid sync. Block = (image n, row-quarter q); all
// intermediates live in LDS; cross-block halo handled by RECOMPUTE
// (y1: 105/63 rows = 1.67x conv1; y2: 49/31; y3: 21/15).
// Strip ranges (inclusive), derived bottom-up from owned out rows
// olo=2q..ohi=min(6,2q+1):
//   y3: [max(0,4q-1), min(14,4q+4)]   (<=6 rows)
//   y2: [max(0,8q-3), min(30,8q+10)]  (<=14 rows)
//   y1: [max(0,16q-7), min(62,16q+22)] (<=30 rows)
// Phase bodies: conv1 = R1 inner loop verbatim (bit-identical fmac
// order; wsgn LDS values == w1s); b2/b3/b4 = R7 rolled general paths
// (bit-identical integer popc/K sums). 512 thr = 8 waves; grid 256 =
// 1 block/CU = 2 waves/SIMD. launch_bounds(512,2) -> VGPR cap 256.
// ============================================================
__global__ __launch_bounds__(512, 2) void mono_k(
        const float* __restrict__ x,  const float* __restrict__ w1,
        const float* __restrict__ m1, const float* __restrict__ v1, const float* __restrict__ b1,
        const uint32_t* __restrict__ w2p,
        const float* __restrict__ m2, const float* __restrict__ v2, const float* __restrict__ b2,
        const uint32_t* __restrict__ w3p,
        const float* __restrict__ m3, const float* __restrict__ v3, const float* __restrict__ b3,
        const uint32_t* __restrict__ w4p,
        const float* __restrict__ m4, const float* __restrict__ v4, const float* __restrict__ b4,
        float* __restrict__ out) {
    __shared__ __align__(16) float    xt[34 * 200];    // conv1 input tile (27.2 KB)
    __shared__ __align__(16) float    wsgn[864];       // conv1 sign weights
    __shared__ uint32_t               y1s[30 * 64];    // y1 strip (packed rows)
    __shared__ uint2                  y2s[14 * 32];    // y2 strip
    __shared__ __align__(16) uint32_t y3s[6 * 15 * 4]; // y3 strip (uint4 px)

    const int blk = blockIdx.x;
    const int q = blk & 3;
    const int n = blk >> 2;
    const int tid = threadIdx.x;
    const int wave = tid >> 6, lane = tid & 63;

    const int y1lo = max(0, 16 * q - 7),  y1hi = min(62, 16 * q + 22);
    const int y2lo = max(0, 8 * q - 3),   y2hi = min(30, 8 * q + 10);
    const int y3lo = max(0, 4 * q - 1),   y3hi = min(14, 4 * q + 4);
    const int olo  = 2 * q,               ohi  = min(6, 2 * q + 1);
    const int ny1 = y1hi - y1lo + 1;      // 22..30
    const int ny2 = y2hi - y2lo + 1;      // 10..14
    const int ny3 = y3hi - y3lo + 1;      // 4..6
    const int no  = ohi - olo + 1;        // 1..2

    // stage sign weights (identical values to w1s)
    for (int i = tid; i < 864; i += 512)
        wsgn[i] = (w1[i] < 0.f) ? -1.f : 1.f;

    // ---- Phase 1: conv1 + pool + bn + sign -> y1s (strip) ----
    {
        int py = (wave & 3) * 4 + (lane >> 4);    // 0..15
        int px = (wave >> 2) * 16 + (lane & 15);  // 0..31
#pragma unroll 1
        for (int rc = 0; rc < 2; rc++) {
            int rowbase = y1lo + rc * 16;
#pragma unroll 1
            for (int cc = 0; cc < 2; cc++) {
                int colbase = cc * 32;
                int r0 = 2 * rowbase;
                int cf0 = colbase * 6;
                __syncthreads();                   // xt safe to overwrite
                for (int i = tid; i < 34 * 198; i += 512) {
                    int r = i / 198, c = i % 198;
                    int gr = r0 + r, gcf = cf0 + c;
                    float vv = 0.f;
                    if (gr < 128 && gcf < 384)
                        vv = x[(size_t)(n * 128 + gr) * 384 + gcf];
                    xt[r * 200 + c] = vv;
                }
                __syncthreads();

                float win[48];
#pragma unroll
                for (int r = 0; r < 4; r++) {
                    const float2* bp = (const float2*)&xt[(2 * py + r) * 200 + 6 * px];
#pragma unroll
                    for (int qq = 0; qq < 6; qq++) {
                        float2 f2 = bp[qq];
                        win[r * 12 + 2 * qq]     = f2.x;
                        win[r * 12 + 2 * qq + 1] = f2.y;
                    }
                }

                uint32_t word = 0;
#pragma unroll 1
                for (int g = 0; g < 4; g++) {
                    float acc[8][4];
#pragma unroll
                    for (int j = 0; j < 8; j++)
#pragma unroll
                        for (int p = 0; p < 4; p++) acc[j][p] = 0.f;

#pragma unroll
                    for (int kh = 0; kh < 3; kh++)
#pragma unroll
                        for (int kw = 0; kw < 3; kw++)
#pragma unroll
                            for (int ci = 0; ci < 3; ci++) {
                                int tap = (kh * 3 + kw) * 3 + ci;
                                float x00 = win[kh * 12 + kw * 3 + ci];
                                float x01 = win[kh * 12 + (kw + 1) * 3 + ci];
                                float x10 = win[(kh + 1) * 12 + kw * 3 + ci];
                                float x11 = win[(kh + 1) * 12 + (kw + 1) * 3 + ci];
                                float4 s0 = *(const float4*)(&wsgn[tap * 32 + g * 8]);
                                float4 s1 = *(const float4*)(&wsgn[tap * 32 + g * 8 + 4]);
                                float sv[8] = {s0.x, s0.y, s0.z, s0.w, s1.x, s1.y, s1.z, s1.w};
#pragma unroll
                                for (int j = 0; j < 8; j++) {
                                    acc[j][0] += x00 * sv[j];
                                    acc[j][1] += x01 * sv[j];
                                    acc[j][2] += x10 * sv[j];
                                    acc[j][3] += x11 * sv[j];
                                }
                            }
#pragma unroll
                    for (int j = 0; j < 8; j++) {
                        float mx = fmaxf(fmaxf(acc[j][0], acc[j][1]), fmaxf(acc[j][2], acc[j][3]));
                        int ch = g * 8 + j;
                        float y = (mx - m1[ch]) * rsqrtf(v1[ch] + BN_EPS) + b1[ch];
                        word |= (uint32_t)(y < 0.f) << ch;
                    }
                }

                int srow = rc * 16 + py;          // strip row
                int pw = colbase + px;
                if (srow < ny1 && pw < 63)
                    y1s[srow * 64 + pw] = word;
            }
        }
    }
    __syncthreads();

    // ---- Phase 2: bconv2 + pool + bn + sign -> y2s (strip) ----
    {
        uint32_t wq[9];
#pragma unroll
        for (int tap = 0; tap < 9; tap++) wq[tap] = w2p[tap * 64 + lane];
        float mm = m2[lane];
        float rs = rsqrtf(v2[lane] + BN_EPS);
        float bb = b2[lane];

        int ntask = ny2 * 31;
#pragma unroll 1
        for (int idx = wave; idx < ntask; idx += 8) {
            int r2 = y2lo + idx / 31;
            int pw = idx % 31;
            int best = -1000000;
#pragma unroll 1
            for (int qq = 0; qq < 4; qq++) {
                int dy = qq >> 1, dx = qq & 1;
                int oh = 2 * r2 + dy, ow = 2 * pw + dx;
                int acc = 0, K = 0;
#pragma unroll
                for (int kh = 0; kh < 3; kh++) {
                    int ih = oh - 1 + kh;
                    bool rok = (ih >= 0) && (ih < 63);
                    int rowS = min(max(ih, y1lo), y1hi) - y1lo;
#pragma unroll
                    for (int kw = 0; kw < 3; kw++) {
                        int iw = ow - 1 + kw;
                        bool ok = rok && (iw >= 0) && (iw < 63);
                        uint32_t wv = y1s[rowS * 64 + min(max(iw, 0), 62)];
                        acc += ok ? __popc(wv ^ wq[kh * 3 + kw]) : 0;
                        K += ok ? 32 : 0;
                    }
                }
                best = max(best, K - 2 * acc);
            }
            float y = ((float)best - mm) * rs + bb;
            unsigned long long bal = __ballot(y < 0.f);
            if (lane == 0)
                y2s[(r2 - y2lo) * 32 + pw] = make_uint2((uint32_t)bal, (uint32_t)(bal >> 32));
        }
    }
    __syncthreads();

    // ---- Phase 3: bconv3 + pool + bn + sign -> y3s (strip) ----
    {
        int half = wave & 1;                  // fixed per wave (stride 4 below)
        int co = half * 64 + lane;
        uint32_t wq0[9], wq1[9];
#pragma unroll
        for (int tap = 0; tap < 9; tap++) {
            wq0[tap] = w3p[(tap * 2 + 0) * 128 + co];
            wq1[tap] = w3p[(tap * 2 + 1) * 128 + co];
        }
        float mm = m3[co];
        float rs = rsqrtf(v3[co] + BN_EPS);
        float bb = b3[co];

        int ntask = ny3 * 15;
#pragma unroll 1
        for (int t2 = (wave >> 1); t2 < ntask; t2 += 4) {
            int r3 = y3lo + t2 / 15;
            int pw = t2 % 15;
            int best = -1000000;
#pragma unroll 1
            for (int qq = 0; qq < 4; qq++) {
                int dy = qq >> 1, dx = qq & 1;
                int oh = 2 * r3 + dy, ow = 2 * pw + dx;
                int acc = 0, K = 0;
#pragma unroll
                for (int kh = 0; kh < 3; kh++) {
                    int ih = oh - 1 + kh;
                    bool rok = (ih >= 0) && (ih < 31);
                    int rowS = min(max(ih, y2lo), y2hi) - y2lo;
#pragma unroll
                    for (int kw = 0; kw < 3; kw++) {
                        int iw = ow - 1 + kw;
                        bool ok = rok && (iw >= 0) && (iw < 31);
                        uint2 iv = y2s[rowS * 32 + min(max(iw, 0), 30)];
                        int tap = kh * 3 + kw;
                        acc += ok ? (__popc(iv.x ^ wq0[tap]) + __popc(iv.y ^ wq1[tap])) : 0;
                        K += ok ? 64 : 0;
                    }
                }
                best = max(best, K - 2 * acc);
            }
            float y = ((float)best - mm) * rs + bb;
            unsigned long long bal = __ballot(y < 0.f);
            uint32_t val = (lane & 1) ? (uint32_t)(bal >> 32) : (uint32_t)bal;
            if (lane < 2)
                y3s[((r3 - y3lo) * 15 + pw) * 4 + half * 2 + lane] = val;
        }
    }
    __syncthreads();

    // ---- Phase 4: bconv4 + pool + bn -> out (global, f32) ----
    {
        int grp = wave & 3;                   // fixed per wave (stride 2 below)
        int co = grp * 64 + lane;
        uint4 wq[9];
#pragma unroll
        for (int tap = 0; tap < 9; tap++) {
            wq[tap].x = w4p[(tap * 4 + 0) * 256 + co];
            wq[tap].y = w4p[(tap * 4 + 1) * 256 + co];
            wq[tap].z = w4p[(tap * 4 + 2) * 256 + co];
            wq[tap].w = w4p[(tap * 4 + 3) * 256 + co];
        }
        float mm = m4[co];
        float rs = rsqrtf(v4[co] + BN_EPS);
        float bb = b4[co];

        int ntask = no * 7;
#pragma unroll 1
        for (int u = (wave >> 2); u < ntask; u += 2) {
            int o = olo + u / 7;
            int pw = u % 7;
            int best = -1000000;
#pragma unroll 1
            for (int qq = 0; qq < 4; qq++) {
                int dy = qq >> 1, dx = qq & 1;
                int oh = 2 * o + dy, ow = 2 * pw + dx;
                int acc = 0, K = 0;
#pragma unroll
                for (int kh = 0; kh < 3; kh++) {
                    int ih = oh - 1 + kh;
                    bool rok = (ih >= 0) && (ih < 15);
                    int rowS = min(max(ih, y3lo), y3hi) - y3lo;
#pragma unroll
                    for (int kw = 0; kw < 3; kw++) {
                        int iw = ow - 1 + kw;
                        bool ok = rok && (iw >= 0) && (iw < 15);
                        const uint4 iv = *(const uint4*)&y3s[(rowS * 15 + min(max(iw, 0), 14)) * 4];
                        int tap = kh * 3 + kw;
                        int pc = __popc(iv.x ^ wq[tap].x) + __popc(iv.y ^ wq[tap].y)
                               + __popc(iv.z ^ wq[tap].z) + __popc(iv.w ^ wq[tap].w);
                        acc += ok ? pc : 0;
                        K += ok ? 128 : 0;
                    }
                }
                best = max(best, K - 2 * acc);
            }
            float y = ((float)best - mm) * rs + bb;
            out[((size_t)(n * 7 + o) * 7 + pw) * 256 + co] = y;
        }
    }
}

extern "C" void kernel_launch(void* const* d_in, const int* in_sizes, int n_in,
                              void* d_out, int out_size, void* d_ws, size_t ws_size,
                              hipStream_t stream) {
    const float* x  = (const float*)d_in[0];
    const float* w1 = (const float*)d_in[1];
    const float* m1 = (const float*)d_in[2];
    const float* v1 = (const float*)d_in[3];
    const float* b1 = (const float*)d_in[4];
    const float* w2 = (const float*)d_in[5];
    const float* m2 = (const float*)d_in[6];
    const float* v2 = (const float*)d_in[7];
    const float* b2 = (const float*)d_in[8];
    const float* w3 = (const float*)d_in[9];
    const float* m3 = (const float*)d_in[10];
    const float* v3 = (const float*)d_in[11];
    const float* b3 = (const float*)d_in[12];
    const float* w4 = (const float*)d_in[13];
    const float* m4 = (const float*)d_in[14];
    const float* v4 = (const float*)d_in[15];
    const float* b4 = (const float*)d_in[16];
    float* out = (float*)d_out;

    char* ws = (char*)d_ws;
    size_t off = 0;
    auto take = [&](size_t bytes) -> char* {
        char* p = ws + off;
        off += (bytes + 255) & ~(size_t)255;
        return p;
    };
    float*    w1s = (float*)take(864 * 4);
    uint32_t* w2p = (uint32_t*)take(576 * 4);
    uint32_t* w3p = (uint32_t*)take(2304 * 4);
    uint32_t* w4p = (uint32_t*)take(9216 * 4);

    pack_all<<<(864 + 576 + 2304 + 9216 + 255) / 256, 256, 0, stream>>>(
        w1, w2, w3, w4, w1s, w2p, w3p, w4p);

    // one block per (image, row-quarter); 512 threads
    mono_k<<<64 * 4, 512, 0, stream>>>(
        x, w1, m1, v1, b1,
        w2p, m2, v2, b2,
        w3p, m3, v3, b3,
        w4p, m4, v4, b4,
        out);
}

// Round 10
// 315.828 us; speedup vs baseline: 1.1405x; 1.1405x over previous
//
#include <hip/hip_runtime.h>
#include <stdint.h>

#define BN_EPS 1e-3f

// ============================================================
// Weight prep:
//  - w1s[864]: sign floats, w1s[tap*32+c] = (w1<0 ? -1.f : 1.f)
//  - w2p/w3p/w4p: bit-packed signs, bit=1 <=> w<0, layout [(tap*CINW+wi)][COUT]
// ============================================================
template <int CIN, int COUT>
__device__ inline void packw(const float* __restrict__ w, uint32_t* __restrict__ wp, int idx) {
    const int CINW = CIN / 32;
    int co = idx % COUT;
    int t2 = idx / COUT;
    int wi = t2 % CINW;
    int tap = t2 / CINW;
    uint32_t word = 0;
#pragma unroll
    for (int bb = 0; bb < 32; bb++) {
        float val = w[((tap * CIN) + wi * 32 + bb) * COUT + co];
        word |= (uint32_t)(val < 0.f) << bb;
    }
    wp[idx] = word;
}

__global__ void pack_all(const float* __restrict__ w1, const float* __restrict__ w2,
                         const float* __restrict__ w3, const float* __restrict__ w4,
                         float* __restrict__ w1s, uint32_t* __restrict__ w2p,
                         uint32_t* __restrict__ w3p, uint32_t* __restrict__ w4p) {
    int idx = blockIdx.x * 256 + threadIdx.x;
    if (idx < 864) {
        w1s[idx] = (w1[idx] < 0.f) ? -1.f : 1.f;
        return;
    }
    idx -= 864;
    if (idx < 576) { packw<32, 64>(w2, w2p, idx); return; }
    idx -= 576;
    if (idx < 2304) { packw<64, 128>(w3, w3p, idx); return; }
    idx -= 2304;
    if (idx < 9216) { packw<128, 256>(w4, w4p, idx); return; }
}

// ============================================================
// Layer 1: conv(x, sign(w1), VALID) + maxpool2 + bn + sign -> packed u32.
// (R1 version verbatim -- 45 us measured; control kernel)
// ============================================================
__global__ __launch_bounds__(256, 4) void conv1_k(const float* __restrict__ x,
                                                  const float* __restrict__ w1s,
                                                  const float* __restrict__ m1,
                                                  const float* __restrict__ v1,
                                                  const float* __restrict__ b1,
                                                  uint32_t* __restrict__ y1p) {
    __shared__ __align__(16) float xt[34 * 104];

    int tile = blockIdx.x;
    int tx = tile & 3;
    int ty = (tile >> 2) & 3;
    int n  = tile >> 4;
    int ph0 = ty * 16, pw0 = tx * 16;
    int r0 = 2 * ph0;
    int cf0 = pw0 * 6;

    for (int i = threadIdx.x; i < 34 * 102; i += 256) {
        int r = i / 102, c = i % 102;
        int gr = r0 + r, gcf = cf0 + c;
        float vv = 0.f;
        if (gr < 128 && gcf < 384)
            vv = x[(size_t)(n * 128 + gr) * 384 + gcf];
        xt[r * 104 + c] = vv;
    }
    __syncthreads();

    int wave = threadIdx.x >> 6, lane = threadIdx.x & 63;
    int px = lane & 15, py = (wave << 2) + (lane >> 4);
    int ph = ph0 + py, pw = pw0 + px;

    float win[48];
#pragma unroll
    for (int r = 0; r < 4; r++) {
        const float2* bp = (const float2*)&xt[(2 * py + r) * 104 + 6 * px];
#pragma unroll
        for (int q = 0; q < 6; q++) {
            float2 f2 = bp[q];
            win[r * 12 + 2 * q]     = f2.x;
            win[r * 12 + 2 * q + 1] = f2.y;
        }
    }

    uint32_t word = 0;
#pragma unroll 1
    for (int g = 0; g < 4; g++) {
        float acc[8][4];
#pragma unroll
        for (int j = 0; j < 8; j++)
#pragma unroll
            for (int p = 0; p < 4; p++) acc[j][p] = 0.f;

        const float* sgc = w1s + g * 8;
#pragma unroll
        for (int kh = 0; kh < 3; kh++)
#pragma unroll
            for (int kw = 0; kw < 3; kw++)
#pragma unroll
                for (int ci = 0; ci < 3; ci++) {
                    int tap = (kh * 3 + kw) * 3 + ci;
                    float x00 = win[kh * 12 + kw * 3 + ci];
                    float x01 = win[kh * 12 + (kw + 1) * 3 + ci];
                    float x10 = win[(kh + 1) * 12 + kw * 3 + ci];
                    float x11 = win[(kh + 1) * 12 + (kw + 1) * 3 + ci];
                    float4 s0 = *(const float4*)(sgc + tap * 32);
                    float4 s1 = *(const float4*)(sgc + tap * 32 + 4);
                    float sv[8] = {s0.x, s0.y, s0.z, s0.w, s1.x, s1.y, s1.z, s1.w};
#pragma unroll
                    for (int j = 0; j < 8; j++) {
                        acc[j][0] += x00 * sv[j];
                        acc[j][1] += x01 * sv[j];
                        acc[j][2] += x10 * sv[j];
                        acc[j][3] += x11 * sv[j];
                    }
                }
#pragma unroll
        for (int j = 0; j < 8; j++) {
            float mx = fmaxf(fmaxf(acc[j][0], acc[j][1]), fmaxf(acc[j][2], acc[j][3]));
            int ch = g * 8 + j;
            float y = (mx - m1[ch]) * rsqrtf(v1[ch] + BN_EPS) + b1[ch];
            word |= (uint32_t)(y < 0.f) << ch;
        }
    }

    if (ph < 63 && pw < 63)
        y1p[(n * 63 + ph) * 63 + pw] = word;
}

// ============================================================
// FUSED bconv2 -> bconv3 -> bconv4: one dispatch replaces the three
// latency-bound kernels. Block = (image n, row-quarter q), 512 threads.
// y1 strip staged from global y1p (coalesced); y2/y3 strips in LDS.
// Phase bodies are VERBATIM mono_k phases 2-4 (absmax-0.0-verified R8):
// identical integer popc/K sums, identical BN/ballot/store logic --
// only the y1 source changed from in-kernel compute to global stage.
// Strip ranges (inclusive):
//   y2: [max(0,8q-3), min(30,8q+10)]  (<=14 rows)
//   y1: [max(0,16q-7), min(62,16q+22)] (<=30 rows)
//   y3: [max(0,4q-1), min(14,4q+4)]   (<=6 rows)
//   out rows: olo=2q .. ohi=min(6,2q+1)
// ============================================================
__global__ __launch_bounds__(512, 2) void fused_b234(
        const uint32_t* __restrict__ y1p,
        const uint32_t* __restrict__ w2p,
        const float* __restrict__ m2, const float* __restrict__ v2, const float* __restrict__ b2,
        const uint32_t* __restrict__ w3p,
        const float* __restrict__ m3, const float* __restrict__ v3, const float* __restrict__ b3,
        const uint32_t* __restrict__ w4p,
        const float* __restrict__ m4, const float* __restrict__ v4, const float* __restrict__ b4,
        float* __restrict__ out) {
    __shared__ uint32_t               y1s[30 * 64];    // y1 strip (packed rows)
    __shared__ uint2                  y2s[14 * 32];    // y2 strip
    __shared__ __align__(16) uint32_t y3s[6 * 15 * 4]; // y3 strip (uint4 px)

    const int blk = blockIdx.x;
    const int q = blk & 3;
    const int n = blk >> 2;
    const int tid = threadIdx.x;
    const int wave = tid >> 6, lane = tid & 63;

    const int y1lo = max(0, 16 * q - 7),  y1hi = min(62, 16 * q + 22);
    const int y2lo = max(0, 8 * q - 3),   y2hi = min(30, 8 * q + 10);
    const int y3lo = max(0, 4 * q - 1),   y3hi = min(14, 4 * q + 4);
    const int olo  = 2 * q,               ohi  = min(6, 2 * q + 1);
    const int ny1 = y1hi - y1lo + 1;      // 22..30
    const int ny2 = y2hi - y2lo + 1;      // 10..14
    const int ny3 = y3hi - y3lo + 1;      // 4..6
    const int no  = ohi - olo + 1;        // 1..2

    // ---- Stage y1 strip from global (coalesced rows) ----
    for (int i = tid; i < ny1 * 63; i += 512) {
        int r = i / 63, c = i % 63;
        y1s[r * 64 + c] = y1p[(n * 63 + y1lo + r) * 63 + c];
    }
    __syncthreads();

    // ---- Phase 2: bconv2 + pool + bn + sign -> y2s (strip) ----
    {
        uint32_t wq[9];
#pragma unroll
        for (int tap = 0; tap < 9; tap++) wq[tap] = w2p[tap * 64 + lane];
        float mm = m2[lane];
        float rs = rsqrtf(v2[lane] + BN_EPS);
        float bb = b2[lane];

        int ntask = ny2 * 31;
#pragma unroll 1
        for (int idx = wave; idx < ntask; idx += 8) {
            int r2 = y2lo + idx / 31;
            int pw = idx % 31;
            int best = -1000000;
#pragma unroll 1
            for (int qq = 0; qq < 4; qq++) {
                int dy = qq >> 1, dx = qq & 1;
                int oh = 2 * r2 + dy, ow = 2 * pw + dx;
                int acc = 0, K = 0;
#pragma unroll
                for (int kh = 0; kh < 3; kh++) {
                    int ih = oh - 1 + kh;
                    bool rok = (ih >= 0) && (ih < 63);
                    int rowS = min(max(ih, y1lo), y1hi) - y1lo;
#pragma unroll
                    for (int kw = 0; kw < 3; kw++) {
                        int iw = ow - 1 + kw;
                        bool ok = rok && (iw >= 0) && (iw < 63);
                        uint32_t wv = y1s[rowS * 64 + min(max(iw, 0), 62)];
                        acc += ok ? __popc(wv ^ wq[kh * 3 + kw]) : 0;
                        K += ok ? 32 : 0;
                    }
                }
                best = max(best, K - 2 * acc);
            }
            float y = ((float)best - mm) * rs + bb;
            unsigned long long bal = __ballot(y < 0.f);
            if (lane == 0)
                y2s[(r2 - y2lo) * 32 + pw] = make_uint2((uint32_t)bal, (uint32_t)(bal >> 32));
        }
    }
    __syncthreads();

    // ---- Phase 3: bconv3 + pool + bn + sign -> y3s (strip) ----
    {
        int half = wave & 1;                  // fixed per wave (stride 4 below)
        int co = half * 64 + lane;
        uint32_t wq0[9], wq1[9];
#pragma unroll
        for (int tap = 0; tap < 9; tap++) {
            wq0[tap] = w3p[(tap * 2 + 0) * 128 + co];
            wq1[tap] = w3p[(tap * 2 + 1) * 128 + co];
        }
        float mm = m3[co];
        float rs = rsqrtf(v3[co] + BN_EPS);
        float bb = b3[co];

        int ntask = ny3 * 15;
#pragma unroll 1
        for (int t2 = (wave >> 1); t2 < ntask; t2 += 4) {
            int r3 = y3lo + t2 / 15;
            int pw = t2 % 15;
            int best = -1000000;
#pragma unroll 1
            for (int qq = 0; qq < 4; qq++) {
                int dy = qq >> 1, dx = qq & 1;
                int oh = 2 * r3 + dy, ow = 2 * pw + dx;
                int acc = 0, K = 0;
#pragma unroll
                for (int kh = 0; kh < 3; kh++) {
                    int ih = oh - 1 + kh;
                    bool rok = (ih >= 0) && (ih < 31);
                    int rowS = min(max(ih, y2lo), y2hi) - y2lo;
#pragma unroll
                    for (int kw = 0; kw < 3; kw++) {
                        int iw = ow - 1 + kw;
                        bool ok = rok && (iw >= 0) && (iw < 31);
                        uint2 iv = y2s[rowS * 32 + min(max(iw, 0), 30)];
                        int tap = kh * 3 + kw;
                        acc += ok ? (__popc(iv.x ^ wq0[tap]) + __popc(iv.y ^ wq1[tap])) : 0;
                        K += ok ? 64 : 0;
                    }
                }
                best = max(best, K - 2 * acc);
            }
            float y = ((float)best - mm) * rs + bb;
            unsigned long long bal = __ballot(y < 0.f);
            uint32_t val = (lane & 1) ? (uint32_t)(bal >> 32) : (uint32_t)bal;
            if (lane < 2)
                y3s[((r3 - y3lo) * 15 + pw) * 4 + half * 2 + lane] = val;
        }
    }
    __syncthreads();

    // ---- Phase 4: bconv4 + pool + bn -> out (global, f32) ----
    {
        int grp = wave & 3;                   // fixed per wave (stride 2 below)
        int co = grp * 64 + lane;
        uint4 wq[9];
#pragma unroll
        for (int tap = 0; tap < 9; tap++) {
            wq[tap].x = w4p[(tap * 4 + 0) * 256 + co];
            wq[tap].y = w4p[(tap * 4 + 1) * 256 + co];
            wq[tap].z = w4p[(tap * 4 + 2) * 256 + co];
            wq[tap].w = w4p[(tap * 4 + 3) * 256 + co];
        }
        float mm = m4[co];
        float rs = rsqrtf(v4[co] + BN_EPS);
        float bb = b4[co];

        int ntask = no * 7;
#pragma unroll 1
        for (int u = (wave >> 2); u < ntask; u += 2) {
            int o = olo + u / 7;
            int pw = u % 7;
            int best = -1000000;
#pragma unroll 1
            for (int qq = 0; qq < 4; qq++) {
                int dy = qq >> 1, dx = qq & 1;
                int oh = 2 * o + dy, ow = 2 * pw + dx;
                int acc = 0, K = 0;
#pragma unroll
                for (int kh = 0; kh < 3; kh++) {
                    int ih = oh - 1 + kh;
                    bool rok = (ih >= 0) && (ih < 15);
                    int rowS = min(max(ih, y3lo), y3hi) - y3lo;
#pragma unroll
                    for (int kw = 0; kw < 3; kw++) {
                        int iw = ow - 1 + kw;
                        bool ok = rok && (iw >= 0) && (iw < 15);
                        const uint4 iv = *(const uint4*)&y3s[(rowS * 15 + min(max(iw, 0), 14)) * 4];
                        int tap = kh * 3 + kw;
                        int pc = __popc(iv.x ^ wq[tap].x) + __popc(iv.y ^ wq[tap].y)
                               + __popc(iv.z ^ wq[tap].z) + __popc(iv.w ^ wq[tap].w);
                        acc += ok ? pc : 0;
                        K += ok ? 128 : 0;
                    }
                }
                best = max(best, K - 2 * acc);
            }
            float y = ((float)best - mm) * rs + bb;
            out[((size_t)(n * 7 + o) * 7 + pw) * 256 + co] = y;
        }
    }
}

extern "C" void kernel_launch(void* const* d_in, const int* in_sizes, int n_in,
                              void* d_out, int out_size, void* d_ws, size_t ws_size,
                              hipStream_t stream) {
    const float* x  = (const float*)d_in[0];
    const float* w1 = (const float*)d_in[1];
    const float* m1 = (const float*)d_in[2];
    const float* v1 = (const float*)d_in[3];
    const float* b1 = (const float*)d_in[4];
    const float* w2 = (const float*)d_in[5];
    const float* m2 = (const float*)d_in[6];
    const float* v2 = (const float*)d_in[7];
    const float* b2 = (const float*)d_in[8];
    const float* w3 = (const float*)d_in[9];
    const float* m3 = (const float*)d_in[10];
    const float* v3 = (const float*)d_in[11];
    const float* b3 = (const float*)d_in[12];
    const float* w4 = (const float*)d_in[13];
    const float* m4 = (const float*)d_in[14];
    const float* v4 = (const float*)d_in[15];
    const float* b4 = (const float*)d_in[16];
    float* out = (float*)d_out;

    char* ws = (char*)d_ws;
    size_t off = 0;
    auto take = [&](size_t bytes) -> char* {
        char* p = ws + off;
        off += (bytes + 255) & ~(size_t)255;
        return p;
    };
    uint32_t* y1p = (uint32_t*)take((size_t)64 * 63 * 63 * 4);
    float*    w1s = (float*)take(864 * 4);
    uint32_t* w2p = (uint32_t*)take(576 * 4);
    uint32_t* w3p = (uint32_t*)take(2304 * 4);
    uint32_t* w4p = (uint32_t*)take(9216 * 4);

    pack_all<<<(864 + 576 + 2304 + 9216 + 255) / 256, 256, 0, stream>>>(
        w1, w2, w3, w4, w1s, w2p, w3p, w4p);

    conv1_k<<<64 * 16, 256, 0, stream>>>(x, w1s, m1, v1, b1, y1p);

    // one block per (image, row-quarter); 512 threads
    fused_b234<<<64 * 4, 512, 0, stream>>>(
        y1p,
        w2p, m2, v2, b2,
        w3p, m3, v3, b3,
        w4p, m4, v4, b4,
        out);
}